// Round 3
// baseline (284.304 us; speedup 1.0000x reference)
//
#include <hip/hip_runtime.h>

#define IN_CH    16
#define OUT_CH   64
#define EXP_CH   4096
#define SET_LEN  64
#define BB       8
#define HH       56
#define WW       56

#define TILEROWS 8              // output rows per block (56 = 7*8, no waste)
#define NTILES   7
#define LDSROWS  (TILEROWS + 2) // staged rows incl. halo
#define LROW     58             // (WW + 2) halo columns
#define LDS_XN   (IN_CH * LDSROWS * LROW)

// workspace layout: [0,16K) sorted channel ids (int), [16K, 16K+160K) sorted weights+bias
#define WS_C_OFF   0
#define WS_W_OFF   (OUT_CH * SET_LEN * 4)                  // 16384
#define WS_NEEDED  (WS_W_OFF + OUT_CH * SET_LEN * 10 * 4)  // 180224

// ---------------- pre-kernel: per-oc counting sort + weight gather ----------------
__global__ __launch_bounds__(64)
void rptn_presort(const float* __restrict__ w, const float* __restrict__ bias,
                  const int* __restrict__ idx, int* __restrict__ ws_c,
                  float* __restrict__ ws_w) {
    const int oc = blockIdx.x;
    const int t  = threadIdx.x;
    __shared__ int cnt[IN_CH], pos[IN_CH], eord[SET_LEN];

    if (t < IN_CH) cnt[t] = 0;
    __syncthreads();
    const int e = idx[oc * SET_LEN + t];
    const int c = e >> 8;
    atomicAdd(&cnt[c], 1);
    __syncthreads();
    if (t == 0) {
        int run = 0;
        for (int i = 0; i < IN_CH; ++i) { pos[i] = run; run += cnt[i]; }
    }
    __syncthreads();
    const int p = atomicAdd(&pos[c], 1);
    eord[p] = e;
    __syncthreads();

    const int   es  = eord[t];
    ws_c[oc * SET_LEN + t] = es >> 8;
    float*       dst = ws_w + (oc * SET_LEN + t) * 10;
    const float* src = w + es * 9;
    #pragma unroll
    for (int i = 0; i < 9; ++i) dst[i] = src[i];
    dst[9] = bias[es];
}

// ---------------- main fused kernel ----------------
template <bool USE_WS>
__global__ __launch_bounds__(256, 4)
void rptn_fused_kernel(const float* __restrict__ x,
                       const float* __restrict__ w,
                       const float* __restrict__ bias,
                       const int*   __restrict__ idx,
                       const int*   __restrict__ ws_c,
                       const float* __restrict__ ws_w,
                       float*       __restrict__ out) {
    const int oc   = blockIdx.x;   // fastest-varying -> x tile reused across oc in L2
    const int tile = blockIdx.y;
    const int b    = blockIdx.z;
    const int tid  = threadIdx.x;
    const int tx   = tid & 63;
    const int grp  = __builtin_amdgcn_readfirstlane(tid >> 6); // wave-uniform row group

    __shared__ float s_x[LDS_XN];
    __shared__ int   s_cnt[IN_CH];
    __shared__ int   s_pos[IN_CH];
    __shared__ int   s_eord[SET_LEN];

    // ---- (fallback only) counting-sort set entries by source channel ----
    if (!USE_WS) {
        if (tid < IN_CH) s_cnt[tid] = 0;
        __syncthreads();
        if (tid < SET_LEN) {
            int e = idx[oc * SET_LEN + tid];
            atomicAdd(&s_cnt[e >> 8], 1);
            s_eord[tid] = e; // temp; re-scattered below
        }
        __syncthreads();
        if (tid == 0) {
            int run = 0;
            for (int c = 0; c < IN_CH; ++c) { s_pos[c] = run; run += s_cnt[c]; }
        }
        __syncthreads();
        if (tid < SET_LEN) {
            int e = s_eord[tid];
            __syncthreads(); // all reads of temp done before scatter
            int p = atomicAdd(&s_pos[e >> 8], 1);
            s_eord[p] = e;
        } else {
            __syncthreads();
        }
    }

    // ---- stage x tile (+halo ring, zero-padded) into LDS ----
    // wave-uniform (c,row) per iteration; lanes carry columns.
    const int r0 = tile * TILEROWS;
    const float* xb = x + (size_t)b * IN_CH * HH * WW;
    const bool lanew = (tx < 58);
    const bool lanev = (tx < 56);
    const int  lcol  = lanev ? (tx + 1) : (tx == 56 ? 0 : 57);
    const int  gcol  = lanev ? tx : 0;
    #pragma unroll
    for (int it = 0; it < (IN_CH * LDSROWS) / 4; ++it) {   // 40 iters
        const int linear = it * 4 + grp;                   // scalar
        const int c = linear / 10;
        const int r = linear - c * 10;
        const int gr = r0 - 1 + r;
        float v = 0.0f;
        if ((unsigned)gr < (unsigned)HH) {                 // uniform branch
            v = xb[(c * HH + gr) * WW + gcol];
            if (!lanev) v = 0.0f;
        }
        if (lanew) s_x[(c * LDSROWS + r) * LROW + lcol] = v;
    }
    __syncthreads();

    // ---- per-pixel fused conv + bias + running max; 2 rows per lane ----
    const int txr = lanev ? tx : 0;            // clamp for safe LDS reads
    float acc0 = -__builtin_inff();
    float acc1 = -__builtin_inff();
    int ccur = -1;
    float n00=0,n01=0,n02=0, n10=0,n11=0,n12=0, n20=0,n21=0,n22=0, n30=0,n31=0,n32=0;

    const int*   se = USE_WS ? (ws_c + oc * SET_LEN) : nullptr;
    const float* sw = USE_WS ? (ws_w + oc * SET_LEN * 10) : nullptr;

    #pragma unroll 8
    for (int k = 0; k < SET_LEN; ++k) {
        int c, e = 0;
        if (USE_WS) {
            c = se[k];                                    // uniform s_load
        } else {
            e = __builtin_amdgcn_readfirstlane(s_eord[k]);
            c = e >> 8;
        }
        if (c != ccur) {                                  // uniform branch
            ccur = c;
            const float* sp = &s_x[(c * LDSROWS + grp * 2) * LROW + txr];
            n00 = sp[0];        n01 = sp[1];          n02 = sp[2];
            n10 = sp[LROW];     n11 = sp[LROW + 1];   n12 = sp[LROW + 2];
            n20 = sp[2*LROW];   n21 = sp[2*LROW + 1]; n22 = sp[2*LROW + 2];
            n30 = sp[3*LROW];   n31 = sp[3*LROW + 1]; n32 = sp[3*LROW + 2];
        }
        float w0,w1,w2,w3,w4,w5,w6,w7,w8,bv;
        if (USE_WS) {
            const float* wk = sw + k * 10;                // sequential uniform s_loads
            w0=wk[0]; w1=wk[1]; w2=wk[2]; w3=wk[3]; w4=wk[4];
            w5=wk[5]; w6=wk[6]; w7=wk[7]; w8=wk[8]; bv=wk[9];
        } else {
            const float* wk = w + e * 9;
            w0=wk[0]; w1=wk[1]; w2=wk[2]; w3=wk[3]; w4=wk[4];
            w5=wk[5]; w6=wk[6]; w7=wk[7]; w8=wk[8]; bv=bias[e];
        }
        // pixel 0: rows 0..2 ; pixel 1: rows 1..3  (3 short chains each for ILP)
        float a0 = fmaf(w2,n02, fmaf(w1,n01, fmaf(w0,n00, bv)));
        float a1 = fmaf(w5,n12, fmaf(w4,n11, w3*n10));
        float a2 = fmaf(w8,n22, fmaf(w7,n21, w6*n20));
        acc0 = fmaxf(acc0, a0 + (a1 + a2));
        float b0 = fmaf(w2,n12, fmaf(w1,n11, fmaf(w0,n10, bv)));
        float b1 = fmaf(w5,n22, fmaf(w4,n21, w3*n20));
        float b2 = fmaf(w8,n32, fmaf(w7,n31, w6*n30));
        acc1 = fmaxf(acc1, b0 + (b1 + b2));
    }

    if (lanev) {
        const size_t o = (((size_t)b * OUT_CH + oc) * HH + (r0 + grp * 2)) * WW + tx;
        out[o]      = acc0;
        out[o + WW] = acc1;
    }
}

extern "C" void kernel_launch(void* const* d_in, const int* in_sizes, int n_in,
                              void* d_out, int out_size, void* d_ws, size_t ws_size,
                              hipStream_t stream) {
    const float* x    = (const float*)d_in[0];
    const float* w    = (const float*)d_in[1];
    const float* bias = (const float*)d_in[2];
    const int*   idx  = (const int*)d_in[3];
    float*       out  = (float*)d_out;

    dim3 grid(OUT_CH, NTILES, BB);
    dim3 block(256);

    if (ws_size >= (size_t)WS_NEEDED) {
        int*   ws_c = (int*)((char*)d_ws + WS_C_OFF);
        float* ws_w = (float*)((char*)d_ws + WS_W_OFF);
        rptn_presort<<<dim3(OUT_CH), dim3(64), 0, stream>>>(w, bias, idx, ws_c, ws_w);
        rptn_fused_kernel<true><<<grid, block, 0, stream>>>(x, w, bias, idx, ws_c, ws_w, out);
    } else {
        rptn_fused_kernel<false><<<grid, block, 0, stream>>>(x, w, bias, idx, nullptr, nullptr, out);
    }
}

// Round 6
// 170.010 us; speedup vs baseline: 1.6723x; 1.6723x over previous
//
#include <hip/hip_runtime.h>

#define IN_CH    16
#define OUT_CH   64
#define SET_LEN  64
#define BB       8
#define HH       56
#define WW       56

#define TILEROWS 8              // output rows per block (56 = 7*8)
#define NTILES   7
#define LDSROWS  (TILEROWS + 2) // staged rows incl. halo
#define LROW     58             // (WW + 2) halo columns
#define LDS_XN   (IN_CH * LDSROWS * LROW)   // 9280 floats = 37120 B

typedef float f32x2 __attribute__((ext_vector_type(2)));

__global__ __launch_bounds__(256, 4)
void rptn_fused_kernel(const float* __restrict__ x,
                       const float* __restrict__ w,
                       const float* __restrict__ bias,
                       const int*   __restrict__ idx,
                       float*       __restrict__ out) {
    const int oc   = blockIdx.x;   // fastest-varying -> x tile reused across oc in L2
    const int tile = blockIdx.y;
    const int b    = blockIdx.z;
    const int tid  = threadIdx.x;
    const int tx   = tid & 63;
    const int grp  = __builtin_amdgcn_readfirstlane(tid >> 6); // wave-uniform

    __shared__ float s_x[LDS_XN];
    __shared__ int   s_cnt[IN_CH];
    __shared__ int   s_pos[IN_CH];
    __shared__ int   s_eord[SET_LEN];

    // ---- counting-sort set entries by source channel (e >> 8), R1 pattern ----
    if (tid < IN_CH) s_cnt[tid] = 0;
    __syncthreads();
    int my_e = 0;
    if (tid < SET_LEN) {
        my_e = idx[oc * SET_LEN + tid];
        atomicAdd(&s_cnt[my_e >> 8], 1);
    }
    __syncthreads();
    if (tid == 0) {
        int run = 0;
        for (int c = 0; c < IN_CH; ++c) { s_pos[c] = run; run += s_cnt[c]; }
    }
    __syncthreads();
    if (tid < SET_LEN) {
        int p = atomicAdd(&s_pos[my_e >> 8], 1);
        s_eord[p] = my_e;
    }

    // ---- stage x tile (+halo ring, zero-padded) into LDS, R1 pattern ----
    const int r0 = tile * TILEROWS;
    const float* xb = x + (size_t)b * IN_CH * HH * WW;
    for (int i = tid; i < LDS_XN; i += 256) {
        int c   = i / (LDSROWS * LROW);
        int rem = i - c * (LDSROWS * LROW);
        int r   = rem / LROW;
        int col = rem - r * LROW;
        int gr  = r0 - 1 + r;
        int gc  = col - 1;
        float v = 0.0f;
        if ((unsigned)gr < (unsigned)HH && (unsigned)gc < (unsigned)WW)
            v = xb[(c * HH + gr) * WW + gc];
        s_x[i] = v;
    }
    __syncthreads();

    // ---- fused conv + bias + running max; 2 rows per lane, packed fp32 ----
    const bool lanev = (tx < WW);
    const int  txr   = lanev ? tx : 0;      // clamp for safe LDS reads

    f32x2 acc = { -__builtin_inff(), -__builtin_inff() };
    int ccur = -1;
    f32x2 v00={0,0},v01={0,0},v02={0,0};
    f32x2 v10={0,0},v11={0,0},v12={0,0};
    f32x2 v20={0,0},v21={0,0},v22={0,0};

    #pragma unroll 2
    for (int k = 0; k < SET_LEN; ++k) {
        const int e = __builtin_amdgcn_readfirstlane(s_eord[k]);
        const int c = e >> 8;
        if (c != ccur) {                    // wave-uniform branch
            ccur = c;
            const float* sp = &s_x[(c * LDSROWS + grp * 2) * LROW + txr];
            const float n00=sp[0],        n01=sp[1],          n02=sp[2];
            const float n10=sp[LROW],     n11=sp[LROW+1],     n12=sp[LROW+2];
            const float n20=sp[2*LROW],   n21=sp[2*LROW+1],   n22=sp[2*LROW+2];
            const float n30=sp[3*LROW],   n31=sp[3*LROW+1],   n32=sp[3*LROW+2];
            v00 = (f32x2){n00,n10}; v01 = (f32x2){n01,n11}; v02 = (f32x2){n02,n12};
            v10 = (f32x2){n10,n20}; v11 = (f32x2){n11,n21}; v12 = (f32x2){n12,n22};
            v20 = (f32x2){n20,n30}; v21 = (f32x2){n21,n31}; v22 = (f32x2){n22,n32};
        }
        const float* wp = w + e * 9;        // uniform -> scalar s_loads
        const float w0=wp[0],w1=wp[1],w2=wp[2],w3=wp[3],w4=wp[4];
        const float w5=wp[5],w6=wp[6],w7=wp[7],w8=wp[8];
        const float bv = bias[e];
        // three short packed chains per entry (both pixels share the weights)
        f32x2 t0 = __builtin_elementwise_fma((f32x2){w2,w2}, v02,
                   __builtin_elementwise_fma((f32x2){w1,w1}, v01,
                   __builtin_elementwise_fma((f32x2){w0,w0}, v00, (f32x2){bv,bv})));
        f32x2 t1 = __builtin_elementwise_fma((f32x2){w5,w5}, v12,
                   __builtin_elementwise_fma((f32x2){w4,w4}, v11,
                                             (f32x2){w3,w3} * v10));
        f32x2 t2 = __builtin_elementwise_fma((f32x2){w8,w8}, v22,
                   __builtin_elementwise_fma((f32x2){w7,w7}, v21,
                                             (f32x2){w6,w6} * v20));
        acc = __builtin_elementwise_max(acc, t0 + (t1 + t2));
    }

    if (lanev) {
        const size_t o = (((size_t)b * OUT_CH + oc) * HH + (r0 + grp * 2)) * WW + tx;
        out[o]      = acc.x;   // row grp*2
        out[o + WW] = acc.y;   // row grp*2 + 1
    }
}

extern "C" void kernel_launch(void* const* d_in, const int* in_sizes, int n_in,
                              void* d_out, int out_size, void* d_ws, size_t ws_size,
                              hipStream_t stream) {
    const float* x    = (const float*)d_in[0];
    const float* w    = (const float*)d_in[1];
    const float* bias = (const float*)d_in[2];
    const int*   idx  = (const int*)d_in[3];
    float*       out  = (float*)d_out;

    dim3 grid(OUT_CH, NTILES, BB);   // oc fastest -> x tile L2 reuse
    dim3 block(256);
    rptn_fused_kernel<<<grid, block, 0, stream>>>(x, w, bias, idx, out);
}